// Round 1
// baseline (144.877 us; speedup 1.0000x reference)
//
#include <hip/hip_runtime.h>
#include <math.h>

#define INV_SQRT8 0.35355339059327373f   // (1/sqrt(2))^3

// ws layout (float offsets)
#define WS_S      0        // B*C*8 = 1024 parity sums (needs zeroing)
#define WS_ATTL   1024     // B*64
#define WS_ATTH   1152     // B*448
#define WS_BIAS   2048     // 64
#define WS_SCALE  2112     // 64
#define WS_G      2560     // B*64*64*8 = 65536

// ---------------- kernel 1: parity sums of x per (b,c) ----------------
__global__ __launch_bounds__(256) void k_parity(const float* __restrict__ x,
                                                float* __restrict__ S) {
    int bid = blockIdx.x;                 // B*C*8 = 1024 blocks
    int b = bid >> 9, c = (bid >> 3) & 63, ds = bid & 7;
    const float* xp = x + (((size_t)(b * 64 + c)) * 64 + ds * 8) * 4096;
    int tw = threadIdx.x & 15, th = threadIdx.x >> 4;
    float acc[2][2][2] = {};
    for (int dd = 0; dd < 8; ++dd) {
        int i = dd & 1;
        const float* row0 = xp + dd * 4096;
        for (int hh = 0; hh < 4; ++hh) {
            int h = hh * 16 + th;
            int j = th & 1;
            float4 v = *(const float4*)(row0 + h * 64 + tw * 4);
            acc[i][j][0] += v.x + v.z;
            acc[i][j][1] += v.y + v.w;
        }
    }
    float a[8];
#pragma unroll
    for (int r = 0; r < 8; ++r) a[r] = acc[(r >> 2) & 1][(r >> 1) & 1][r & 1];
#pragma unroll
    for (int off = 1; off < 64; off <<= 1)
#pragma unroll
        for (int r = 0; r < 8; ++r) a[r] += __shfl_xor(a[r], off);
    __shared__ float red[4][8];
    int wave = threadIdx.x >> 6, lane = threadIdx.x & 63;
    if (lane == 0)
        for (int r = 0; r < 8; ++r) red[wave][r] = a[r];
    __syncthreads();
    if (threadIdx.x < 8) {
        float v = red[0][threadIdx.x] + red[1][threadIdx.x] +
                  red[2][threadIdx.x] + red[3][threadIdx.x];
        atomicAdd(&S[(b * 64 + c) * 8 + threadIdx.x], v);
    }
}

// ---------------- kernel 2: subband means -> attention MLPs -> att/scale/bias ----------------
__global__ __launch_bounds__(512) void k_att(const float* __restrict__ Sin,
    const float* __restrict__ lw1, const float* __restrict__ lw2,
    const float* __restrict__ hw1, const float* __restrict__ hw2,
    const float* __restrict__ fuse_b, const float* __restrict__ gamma,
    const float* __restrict__ beta, const float* __restrict__ mean,
    const float* __restrict__ var, float* __restrict__ ws) {
    int b = blockIdx.x, tid = threadIdx.x;
    __shared__ float ml[64], mh[448], hidL[4], hidH[28];
    const float KN = INV_SQRT8 / 32768.0f;
    if (tid < 64) {
        float s8[8];
#pragma unroll
        for (int r = 0; r < 8; ++r) s8[r] = Sin[(b * 64 + tid) * 8 + r];
        float tot = 0;
#pragma unroll
        for (int r = 0; r < 8; ++r) tot += s8[r];
        ml[tid] = tot * KN;
        for (int pq = 1; pq < 8; ++pq) {   // subband code pqr = s'+1
            float v = 0;
#pragma unroll
            for (int r = 0; r < 8; ++r) v += (__popc(pq & r) & 1) ? -s8[r] : s8[r];
            mh[tid * 7 + pq - 1] = v * KN;
        }
    }
    __syncthreads();
    if (tid < 4) {
        float v = 0;
        for (int c = 0; c < 64; ++c) v += ml[c] * lw1[tid * 64 + c];
        hidL[tid] = fmaxf(v, 0.f);
    } else if (tid >= 64 && tid < 92) {
        int hh = tid - 64;
        float v = 0;
        for (int k = 0; k < 448; ++k) v += mh[k] * hw1[hh * 448 + k];
        hidH[hh] = fmaxf(v, 0.f);
    }
    __syncthreads();
    if (tid < 64) {
        float v = 0;
#pragma unroll
        for (int hh = 0; hh < 4; ++hh) v += hidL[hh] * lw2[tid * 4 + hh];
        ws[WS_ATTL + b * 64 + tid] = 1.f / (1.f + expf(-v));
    } else if (tid - 64 < 448) {
        int hc = tid - 64;
        float v = 0;
#pragma unroll
        for (int hh = 0; hh < 28; ++hh) v += hidH[hh] * hw2[hc * 28 + hh];
        ws[WS_ATTH + b * 448 + hc] = 1.f / (1.f + expf(-v));
    }
    if (b == 0 && tid < 64) {
        float sc = gamma[tid] * rsqrtf(var[tid] + 1e-5f);
        ws[WS_SCALE + tid] = sc;
        ws[WS_BIAS + tid] = sc * (fuse_b[tid] - mean[tid]) + beta[tid];
    }
}

// ---------------- kernel 3: effective conv weights G[b][o][c][ijk] ----------------
__global__ __launch_bounds__(64) void k_weights(const float* __restrict__ fuse_w,
                                                float* __restrict__ ws) {
    int b = blockIdx.x >> 6, o = blockIdx.x & 63, c = threadIdx.x;
    const float* attL = ws + WS_ATTL + b * 64;
    const float* attH = ws + WS_ATTH + b * 448;
    float W[8];
    W[0] = fuse_w[o * 512 + c] * attL[c];
#pragma unroll
    for (int s = 1; s < 8; ++s)
        W[s] = fuse_w[o * 512 + 64 + c * 7 + (s - 1)] * attH[c * 7 + s - 1];
    float sc = ws[WS_SCALE + o] * INV_SQRT8;
    float* Gp = ws + WS_G + (((size_t)(b * 64 + o) * 64 + c) * 8);
#pragma unroll
    for (int ijk = 0; ijk < 8; ++ijk) {
        float g = 0;
#pragma unroll
        for (int s = 0; s < 8; ++s) g += (__popc(s & ijk) & 1) ? -W[s] : W[s];
        Gp[ijk] = g * sc;
    }
}

// ---------------- kernel 4: the fused stride-2 2x2x2 conv (per-batch weights) ----------------
__global__ __launch_bounds__(256) void k_conv(const float* __restrict__ x,
                                              const float* __restrict__ ws,
                                              float* __restrict__ out) {
    __shared__ float xs[16 * 4 * 64];     // 16 channels x 4 rows x 64 w  (16 KB)
    __shared__ float Gs[16 * 8 * 65];     // [c'][r] x 64 o, +65 pad     (33 KB)
    int blk = blockIdx.x;                 // 2*32*32 = 2048
    int b = blk >> 10, d = (blk >> 5) & 31, h = blk & 31;
    int tid = threadIdx.x;
    int o = tid & 63, wg = tid >> 6;      // lane = output channel, wave = w-octet
    const float* Gb = ws + WS_G + (size_t)b * 64 * 64 * 8;
    float acc[8] = {};
    for (int c0 = 0; c0 < 64; c0 += 16) {
        __syncthreads();
        // stage x rows: coalesced, 1024 float4
#pragma unroll
        for (int l = 0; l < 4; ++l) {
            int fidx = l * 256 + tid;
            int cc = fidx >> 6, ij = (fidx >> 4) & 3, seg = fidx & 15;
            int i = ij >> 1, j = ij & 1;
            const float* src = x + (((size_t)(b * 64 + c0 + cc)) * 64 + (2 * d + i)) * 4096
                                 + (2 * h + j) * 64 + seg * 4;
            *(float4*)&xs[fidx * 4] = *(const float4*)src;
        }
        // stage G transposed: global-coalesced read, pad-65 conflict-free LDS write
#pragma unroll
        for (int l = 0; l < 32; ++l) {
            int fidx = l * 256 + tid;
            int oo = fidx >> 7, m = fidx & 127;   // m = c'*8 + r
            Gs[m * 65 + oo] = Gb[oo * 512 + (c0 << 3) + m];
        }
        __syncthreads();
        for (int cc = 0; cc < 16; ++cc) {
            float g[8];
#pragma unroll
            for (int r = 0; r < 8; ++r) g[r] = Gs[(cc * 8 + r) * 65 + o];
            float4 xq[4][4];
#pragma unroll
            for (int ij = 0; ij < 4; ++ij)
#pragma unroll
                for (int q = 0; q < 4; ++q)
                    xq[ij][q] = *(float4*)&xs[(cc * 4 + ij) * 64 + wg * 16 + q * 4];
#pragma unroll
            for (int m = 0; m < 8; ++m)
#pragma unroll
                for (int ij = 0; ij < 4; ++ij)
#pragma unroll
                    for (int k = 0; k < 2; ++k) {
                        int e = 2 * m + k;
                        float xv = ((const float*)&xq[ij][e >> 2])[e & 3];
                        acc[m] = fmaf(g[ij * 2 + k], xv, acc[m]);
                    }
        }
    }
    float bias = ws[WS_BIAS + o];
    float* op = out + (((size_t)(b * 64 + o) * 32 + d) * 32 + h) * 32 + wg * 8;
#pragma unroll
    for (int m = 0; m < 8; ++m) op[m] = fmaxf(acc[m] + bias, 0.f);
}

extern "C" void kernel_launch(void* const* d_in, const int* in_sizes, int n_in,
                              void* d_out, int out_size, void* d_ws, size_t ws_size,
                              hipStream_t stream) {
    const float* x      = (const float*)d_in[0];
    const float* lw1    = (const float*)d_in[1];
    const float* lw2    = (const float*)d_in[2];
    const float* hw1    = (const float*)d_in[3];
    const float* hw2    = (const float*)d_in[4];
    const float* fuse_w = (const float*)d_in[5];
    const float* fuse_b = (const float*)d_in[6];
    const float* gamma  = (const float*)d_in[7];
    const float* beta   = (const float*)d_in[8];
    const float* mean   = (const float*)d_in[9];
    const float* var    = (const float*)d_in[10];
    float* ws  = (float*)d_ws;
    float* out = (float*)d_out;

    hipMemsetAsync(d_ws, 0, 1024 * sizeof(float), stream);          // zero parity sums
    k_parity<<<2 * 64 * 8, 256, 0, stream>>>(x, ws + WS_S);
    k_att<<<2, 512, 0, stream>>>(ws + WS_S, lw1, lw2, hw1, hw2,
                                 fuse_b, gamma, beta, mean, var, ws);
    k_weights<<<2 * 64, 64, 0, stream>>>(fuse_w, ws);
    k_conv<<<2 * 32 * 32, 256, 0, stream>>>(x, ws, out);
}

// Round 2
// 103.188 us; speedup vs baseline: 1.4040x; 1.4040x over previous
//
#include <hip/hip_runtime.h>
#include <math.h>

#define INV_SQRT8 0.35355339059327373f   // (1/sqrt(2))^3

// ws layout (float offsets)
#define WS_S      0        // B*C*8 = 1024 parity sums (needs zeroing)
#define WS_ATTL   1024     // B*64
#define WS_ATTH   1152     // B*448
#define WS_BIAS   2048     // 64
#define WS_SCALE  2112     // 64
#define WS_G      2560     // B*512*64 = 65536  (k-major transposed: G[b][c*8+t][o])

// ---------------- kernel 1: parity sums of x per (b,c) ----------------
__global__ __launch_bounds__(256) void k_parity(const float* __restrict__ x,
                                                float* __restrict__ S) {
    int bid = blockIdx.x;                 // B*C*8 = 1024 blocks
    int b = bid >> 9, c = (bid >> 3) & 63, ds = bid & 7;
    const float* xp = x + (((size_t)(b * 64 + c)) * 64 + ds * 8) * 4096;
    int tw = threadIdx.x & 15, th = threadIdx.x >> 4;
    float acc[2][2][2] = {};
    for (int dd = 0; dd < 8; ++dd) {
        int i = dd & 1;
        const float* row0 = xp + dd * 4096;
        for (int hh = 0; hh < 4; ++hh) {
            int h = hh * 16 + th;
            int j = th & 1;
            float4 v = *(const float4*)(row0 + h * 64 + tw * 4);
            acc[i][j][0] += v.x + v.z;
            acc[i][j][1] += v.y + v.w;
        }
    }
    float a[8];
#pragma unroll
    for (int r = 0; r < 8; ++r) a[r] = acc[(r >> 2) & 1][(r >> 1) & 1][r & 1];
#pragma unroll
    for (int off = 1; off < 64; off <<= 1)
#pragma unroll
        for (int r = 0; r < 8; ++r) a[r] += __shfl_xor(a[r], off);
    __shared__ float red[4][8];
    int wave = threadIdx.x >> 6, lane = threadIdx.x & 63;
    if (lane == 0)
        for (int r = 0; r < 8; ++r) red[wave][r] = a[r];
    __syncthreads();
    if (threadIdx.x < 8) {
        float v = red[0][threadIdx.x] + red[1][threadIdx.x] +
                  red[2][threadIdx.x] + red[3][threadIdx.x];
        atomicAdd(&S[(b * 64 + c) * 8 + threadIdx.x], v);
    }
}

// ---------------- kernel 2: subband means -> attention MLPs -> att/scale/bias ----------------
__global__ __launch_bounds__(512) void k_att(const float* __restrict__ Sin,
    const float* __restrict__ lw1, const float* __restrict__ lw2,
    const float* __restrict__ hw1, const float* __restrict__ hw2,
    const float* __restrict__ fuse_b, const float* __restrict__ gamma,
    const float* __restrict__ beta, const float* __restrict__ mean,
    const float* __restrict__ var, float* __restrict__ ws) {
    int b = blockIdx.x, tid = threadIdx.x;
    __shared__ float ml[64], mh[448], hidL[4], hidH[28];
    const float KN = INV_SQRT8 / 32768.0f;
    if (tid < 64) {
        float s8[8];
#pragma unroll
        for (int r = 0; r < 8; ++r) s8[r] = Sin[(b * 64 + tid) * 8 + r];
        float tot = 0;
#pragma unroll
        for (int r = 0; r < 8; ++r) tot += s8[r];
        ml[tid] = tot * KN;
        for (int pq = 1; pq < 8; ++pq) {   // subband code pqr = s'+1
            float v = 0;
#pragma unroll
            for (int r = 0; r < 8; ++r) v += (__popc(pq & r) & 1) ? -s8[r] : s8[r];
            mh[tid * 7 + pq - 1] = v * KN;
        }
    }
    __syncthreads();
    if (tid < 4) {
        float v = 0;
        for (int c = 0; c < 64; ++c) v += ml[c] * lw1[tid * 64 + c];
        hidL[tid] = fmaxf(v, 0.f);
    } else if (tid >= 64 && tid < 92) {
        int hh = tid - 64;
        float v = 0;
        for (int k = 0; k < 448; ++k) v += mh[k] * hw1[hh * 448 + k];
        hidH[hh] = fmaxf(v, 0.f);
    }
    __syncthreads();
    if (tid < 64) {
        float v = 0;
#pragma unroll
        for (int hh = 0; hh < 4; ++hh) v += hidL[hh] * lw2[tid * 4 + hh];
        ws[WS_ATTL + b * 64 + tid] = 1.f / (1.f + expf(-v));
    } else if (tid - 64 < 448) {
        int hc = tid - 64;
        float v = 0;
#pragma unroll
        for (int hh = 0; hh < 28; ++hh) v += hidH[hh] * hw2[hc * 28 + hh];
        ws[WS_ATTH + b * 448 + hc] = 1.f / (1.f + expf(-v));
    }
    if (b == 0 && tid < 64) {
        float sc = gamma[tid] * rsqrtf(var[tid] + 1e-5f);
        ws[WS_SCALE + tid] = sc;
        ws[WS_BIAS + tid] = sc * (fuse_b[tid] - mean[tid]) + beta[tid];
    }
}

// ---------------- kernel 3: effective conv weights, k-major: G[b][(c,t)][o] ----------------
__global__ __launch_bounds__(64) void k_weights(const float* __restrict__ fuse_w,
                                                float* __restrict__ ws) {
    int b = blockIdx.x >> 6, o = blockIdx.x & 63, c = threadIdx.x;
    const float* attL = ws + WS_ATTL + b * 64;
    const float* attH = ws + WS_ATTH + b * 448;
    float W[8];
    W[0] = fuse_w[o * 512 + c] * attL[c];
#pragma unroll
    for (int s = 1; s < 8; ++s)
        W[s] = fuse_w[o * 512 + 64 + c * 7 + (s - 1)] * attH[c * 7 + s - 1];
    float sc = ws[WS_SCALE + o] * INV_SQRT8;
    float* Gp = ws + WS_G + b * 32768 + (c << 3) * 64 + o;   // [kk=(c*8+t)][o]
#pragma unroll
    for (int ijk = 0; ijk < 8; ++ijk) {
        float g = 0;
#pragma unroll
        for (int s = 0; s < 8; ++s) g += (__popc(s & ijk) & 1) ? -W[s] : W[s];
        Gp[ijk * 64] = g * sc;
    }
}

// ---------------- kernel 4: fused stride-2 conv as register-blocked GEMM ----------------
// Block: b, d, h0(4 rows). Computes 64o x 4h x 32w. Thread: 8o x 4w accumulators.
// tid = to(8) + 8*wq(8) + 64*hr(4); wave = one h row.
__global__ __launch_bounds__(256) void k_conv(const float* __restrict__ x,
                                              const float* __restrict__ ws,
                                              float* __restrict__ out) {
    // Xs[cc][ii][hj][k2][36] : de-interleaved w-parity planes, 36-float stride
    __shared__ __align__(16) float Xs[8 * 1152];   // 36 KB
    __shared__ __align__(16) float Gs[64 * 64];    // 16 KB  (total 52 KB)
    int blk = blockIdx.x;                 // 2*32*8 = 512
    int b = blk >> 8, d = (blk >> 3) & 31, h0 = (blk & 7) * 4;
    int tid = threadIdx.x;
    int to = tid & 7, wq = (tid >> 3) & 7, hr = tid >> 6;
    const float* Gb = ws + WS_G + b * 32768;
    const float* xb = x + (size_t)b * 64 * 262144 + (size_t)(2 * d) * 4096 + (2 * h0) * 64;
    float acc[8][4] = {};
    for (int c0 = 0; c0 < 64; c0 += 8) {
        __syncthreads();
        // stage G chunk: 4096 floats, fully coalesced float4
        {
            const float4* gsrc = (const float4*)(Gb + (c0 << 9));
            float4* gdst = (float4*)Gs;
#pragma unroll
            for (int l = 0; l < 4; ++l)
                gdst[l * 256 + tid] = gsrc[l * 256 + tid];
        }
        // stage x chunk with w de-interleave: 8 channels x 2 d-rows x 8 h-rows x 64 w
#pragma unroll
        for (int l = 0; l < 8; ++l) {
            int fidx = l * 256 + tid;
            int row = fidx >> 4, seg = fidx & 15;
            int cc = row >> 4, ii = (row >> 3) & 1, hj = row & 7;
            const float* src = xb + (size_t)(c0 + cc) * 262144 + ii * 4096 + hj * 64 + seg * 4;
            float4 v = *(const float4*)src;
            float* bb = Xs + cc * 1152 + ii * 576 + hj * 72 + seg * 2;
            *(float2*)bb        = make_float2(v.x, v.z);   // even-w plane
            *(float2*)(bb + 36) = make_float2(v.y, v.w);   // odd-w plane
        }
        __syncthreads();
        const float* xh = Xs + hr * 144;   // 2*hr rows into the hj dimension
#pragma unroll 2
        for (int cc = 0; cc < 8; ++cc) {
#pragma unroll
            for (int t = 0; t < 8; ++t) {
                int ii = t >> 2, j = (t >> 1) & 1, k2 = t & 1;
                const float* gp = &Gs[(((cc << 3) + t) << 6) + to * 8];
                float4 g0 = *(const float4*)gp;
                float4 g1 = *(const float4*)(gp + 4);
                float4 xv = *(const float4*)(xh + cc * 1152 + ii * 576 + j * 72 + k2 * 36 + wq * 4);
                float gg[8] = {g0.x, g0.y, g0.z, g0.w, g1.x, g1.y, g1.z, g1.w};
                float xx[4] = {xv.x, xv.y, xv.z, xv.w};
#pragma unroll
                for (int oo = 0; oo < 8; ++oo)
#pragma unroll
                    for (int wwi = 0; wwi < 4; ++wwi)
                        acc[oo][wwi] = fmaf(gg[oo], xx[wwi], acc[oo][wwi]);
            }
        }
    }
    float* ob = out + (((size_t)(b * 64 + to * 8) * 32 + d) * 32 + (h0 + hr)) * 32 + wq * 4;
#pragma unroll
    for (int oo = 0; oo < 8; ++oo) {
        float bias = ws[WS_BIAS + to * 8 + oo];
        float4 r;
        r.x = fmaxf(acc[oo][0] + bias, 0.f);
        r.y = fmaxf(acc[oo][1] + bias, 0.f);
        r.z = fmaxf(acc[oo][2] + bias, 0.f);
        r.w = fmaxf(acc[oo][3] + bias, 0.f);
        *(float4*)(ob + (size_t)oo * 32768) = r;
    }
}

extern "C" void kernel_launch(void* const* d_in, const int* in_sizes, int n_in,
                              void* d_out, int out_size, void* d_ws, size_t ws_size,
                              hipStream_t stream) {
    const float* x      = (const float*)d_in[0];
    const float* lw1    = (const float*)d_in[1];
    const float* lw2    = (const float*)d_in[2];
    const float* hw1    = (const float*)d_in[3];
    const float* hw2    = (const float*)d_in[4];
    const float* fuse_w = (const float*)d_in[5];
    const float* fuse_b = (const float*)d_in[6];
    const float* gamma  = (const float*)d_in[7];
    const float* beta   = (const float*)d_in[8];
    const float* mean   = (const float*)d_in[9];
    const float* var    = (const float*)d_in[10];
    float* ws  = (float*)d_ws;
    float* out = (float*)d_out;

    hipMemsetAsync(d_ws, 0, 1024 * sizeof(float), stream);          // zero parity sums
    k_parity<<<2 * 64 * 8, 256, 0, stream>>>(x, ws + WS_S);
    k_att<<<2, 512, 0, stream>>>(ws + WS_S, lw1, lw2, hw1, hw2,
                                 fuse_b, gamma, beta, mean, var, ws);
    k_weights<<<2 * 64, 64, 0, stream>>>(fuse_w, ws);
    k_conv<<<2 * 32 * 8, 256, 0, stream>>>(x, ws, out);
}

// Round 3
// 60.452 us; speedup vs baseline: 2.3966x; 1.7069x over previous
//
#include <hip/hip_runtime.h>
#include <math.h>

#define INV_SQRT8 0.35355339059327373f   // (1/sqrt(2))^3

typedef __attribute__((ext_vector_type(8))) _Float16 half8;
typedef __attribute__((ext_vector_type(4))) float f32x4;

// ws layout (float offsets)
#define WS_S      0        // B*C*8dslab*8parity = 8192 partial sums (no memset needed)
#define WS_ATTL   8192     // B*64
#define WS_ATTH   8320     // B*448
#define WS_BIAS   9216     // 64
#define WS_SCALE  9280     // 64
#define WS_G      9344     // fragments: 2 * 32768 halfs = 32768 floats

// ---------------- kernel 1: parity partial sums of x per (b,c,d-slab) ----------------
__global__ __launch_bounds__(256) void k_parity(const float* __restrict__ x,
                                                float* __restrict__ S) {
    int bid = blockIdx.x;                 // B*C*8 = 1024 blocks
    int b = bid >> 9, c = (bid >> 3) & 63, ds = bid & 7;
    const float* xp = x + (((size_t)(b * 64 + c)) * 64 + ds * 8) * 4096;
    int tw = threadIdx.x & 15, th = threadIdx.x >> 4;
    float acc[2][2][2] = {};
    for (int dd = 0; dd < 8; ++dd) {
        int i = dd & 1;
        const float* row0 = xp + dd * 4096;
        for (int hh = 0; hh < 4; ++hh) {
            int h = hh * 16 + th;
            int j = th & 1;
            float4 v = *(const float4*)(row0 + h * 64 + tw * 4);
            acc[i][j][0] += v.x + v.z;
            acc[i][j][1] += v.y + v.w;
        }
    }
    float a[8];
#pragma unroll
    for (int r = 0; r < 8; ++r) a[r] = acc[(r >> 2) & 1][(r >> 1) & 1][r & 1];
#pragma unroll
    for (int off = 1; off < 64; off <<= 1)
#pragma unroll
        for (int r = 0; r < 8; ++r) a[r] += __shfl_xor(a[r], off);
    __shared__ float red[4][8];
    int wave = threadIdx.x >> 6, lane = threadIdx.x & 63;
    if (lane == 0)
        for (int r = 0; r < 8; ++r) red[wave][r] = a[r];
    __syncthreads();
    if (threadIdx.x < 8) {
        float v = red[0][threadIdx.x] + red[1][threadIdx.x] +
                  red[2][threadIdx.x] + red[3][threadIdx.x];
        S[((b * 64 + c) * 8 + ds) * 8 + threadIdx.x] = v;   // no atomics
    }
}

// ---------------- kernel 2: subband means -> attention MLPs -> att/scale/bias ----------------
__global__ __launch_bounds__(512) void k_att(const float* __restrict__ Sin,
    const float* __restrict__ lw1, const float* __restrict__ lw2,
    const float* __restrict__ hw1, const float* __restrict__ hw2,
    const float* __restrict__ fuse_b, const float* __restrict__ gamma,
    const float* __restrict__ beta, const float* __restrict__ mean,
    const float* __restrict__ var, float* __restrict__ ws) {
    int b = blockIdx.x, tid = threadIdx.x;
    __shared__ float ml[64], mh[448], hidL[4], hidH[28];
    const float KN = INV_SQRT8 / 32768.0f;
    if (tid < 64) {
        float s8[8];
#pragma unroll
        for (int r = 0; r < 8; ++r) s8[r] = 0.f;
        for (int ds = 0; ds < 8; ++ds)
#pragma unroll
            for (int r = 0; r < 8; ++r)
                s8[r] += Sin[((b * 64 + tid) * 8 + ds) * 8 + r];
        float tot = 0;
#pragma unroll
        for (int r = 0; r < 8; ++r) tot += s8[r];
        ml[tid] = tot * KN;
        for (int pq = 1; pq < 8; ++pq) {   // subband code pqr = s'+1
            float v = 0;
#pragma unroll
            for (int r = 0; r < 8; ++r) v += (__popc(pq & r) & 1) ? -s8[r] : s8[r];
            mh[tid * 7 + pq - 1] = v * KN;
        }
    }
    __syncthreads();
    if (tid < 4) {
        float v = 0;
        for (int c = 0; c < 64; ++c) v += ml[c] * lw1[tid * 64 + c];
        hidL[tid] = fmaxf(v, 0.f);
    } else if (tid >= 64 && tid < 92) {
        int hh = tid - 64;
        float v = 0;
        for (int k = 0; k < 448; ++k) v += mh[k] * hw1[hh * 448 + k];
        hidH[hh] = fmaxf(v, 0.f);
    }
    __syncthreads();
    if (tid < 64) {
        float v = 0;
#pragma unroll
        for (int hh = 0; hh < 4; ++hh) v += hidL[hh] * lw2[tid * 4 + hh];
        ws[WS_ATTL + b * 64 + tid] = 1.f / (1.f + expf(-v));
    } else if (tid - 64 < 448) {
        int hc = tid - 64;
        float v = 0;
#pragma unroll
        for (int hh = 0; hh < 28; ++hh) v += hidH[hh] * hw2[hc * 28 + hh];
        ws[WS_ATTH + b * 448 + hc] = 1.f / (1.f + expf(-v));
    }
    if (b == 0 && tid < 64) {
        float sc = gamma[tid] * rsqrtf(var[tid] + 1e-5f);
        ws[WS_SCALE + tid] = sc;
        ws[WS_BIAS + tid] = sc * (fuse_b[tid] - mean[tid]) + beta[tid];
    }
}

// ---------------- kernel 3: conv weights as f16 MFMA A-fragments ----------------
// Gfrag[b][ks 16][ot 4][lane 64][e 8] half; lane=(c&3)*16+(o&15), e=tap t.
__global__ __launch_bounds__(64) void k_weights(const float* __restrict__ fuse_w,
                                                float* __restrict__ ws) {
    int b = blockIdx.x >> 6, o = blockIdx.x & 63, c = threadIdx.x;
    const float* attL = ws + WS_ATTL + b * 64;
    const float* attH = ws + WS_ATTH + b * 448;
    float W[8];
    W[0] = fuse_w[o * 512 + c] * attL[c];
#pragma unroll
    for (int s = 1; s < 8; ++s)
        W[s] = fuse_w[o * 512 + 64 + c * 7 + (s - 1)] * attH[c * 7 + s - 1];
    float sc = ws[WS_SCALE + o] * INV_SQRT8;
    half8 hv;
#pragma unroll
    for (int t = 0; t < 8; ++t) {
        float g = 0;
#pragma unroll
        for (int s = 0; s < 8; ++s) g += (__popc(s & t) & 1) ? -W[s] : W[s];
        hv[t] = (_Float16)(g * sc);
    }
    _Float16* Gf = (_Float16*)(ws + WS_G);
    size_t idx = (size_t)b * 32768 +
                 ((((size_t)(c >> 2) * 4 + (o >> 4)) * 64) + (c & 3) * 16 + (o & 15)) * 8;
    *(half8*)(Gf + idx) = hv;
}

// ---------------- kernel 4: conv via MFMA f16 ----------------
// Block: (b, d, h0 = 2 rows). Output 64o x 2h x 32w (N=64). 4 waves, wave = one n-tile.
__global__ __launch_bounds__(256) void k_conv(const float* __restrict__ x,
                                              const float* __restrict__ ws,
                                              float* __restrict__ out) {
    __shared__ __align__(16) _Float16 Gs[8192];   // 16KB: [ks4][ot4][lane64][8]
    __shared__ __align__(16) _Float16 Xs[8192];   // 16KB: [c16][n64][cube8]
    int blk = blockIdx.x;                 // 2*32*16 = 1024
    int b = blk >> 9, d = (blk >> 4) & 31, h0 = (blk & 15) * 2;
    int tid = threadIdx.x;
    int lane = tid & 63, wv = tid >> 6;   // wv = n-tile
    const _Float16* Gf = (const _Float16*)(ws + WS_G) + (size_t)b * 32768;
    const float* xb = x + (size_t)b * 64 * 262144 + (size_t)(2 * d) * 4096 + (2 * h0) * 64;
    f32x4 acc[4] = {};                    // per o-tile
    for (int ch = 0; ch < 4; ++ch) {
        __syncthreads();
        // stage A fragments: 16KB linear coalesced copy
        {
            const float4* gsrc = (const float4*)(Gf + ch * 8192);
#pragma unroll
            for (int l = 0; l < 4; ++l)
                ((float4*)Gs)[l * 256 + tid] = gsrc[l * 256 + tid];
        }
        // stage X cubes: 512 (c,hl,seg) combos, 2 per thread
#pragma unroll
        for (int it = 0; it < 2; ++it) {
            int t2 = it * 256 + tid;
            int seg = t2 & 15, hl = (t2 >> 4) & 1, cc = t2 >> 5;
            const float* src = xb + (size_t)(ch * 16 + cc) * 262144 + hl * 128 + seg * 4;
            float4 v00 = *(const float4*)(src);              // i=0 j=0
            float4 v01 = *(const float4*)(src + 64);         // i=0 j=1
            float4 v10 = *(const float4*)(src + 4096);       // i=1 j=0
            float4 v11 = *(const float4*)(src + 4096 + 64);  // i=1 j=1
            half8 cA, cB;
            cA[0] = (_Float16)v00.x; cA[1] = (_Float16)v00.y;
            cA[2] = (_Float16)v01.x; cA[3] = (_Float16)v01.y;
            cA[4] = (_Float16)v10.x; cA[5] = (_Float16)v10.y;
            cA[6] = (_Float16)v11.x; cA[7] = (_Float16)v11.y;
            cB[0] = (_Float16)v00.z; cB[1] = (_Float16)v00.w;
            cB[2] = (_Float16)v01.z; cB[3] = (_Float16)v01.w;
            cB[4] = (_Float16)v10.z; cB[5] = (_Float16)v10.w;
            cB[6] = (_Float16)v11.z; cB[7] = (_Float16)v11.w;
            int n0 = hl * 32 + 2 * seg;
            *(half8*)&Xs[((size_t)cc * 64 + n0) * 8]     = cA;
            *(half8*)&Xs[((size_t)cc * 64 + n0 + 1) * 8] = cB;
        }
        __syncthreads();
#pragma unroll
        for (int ks = 0; ks < 4; ++ks) {
            half8 bfrag = *(const half8*)&Xs[(((size_t)ks * 4 + (lane >> 4)) * 64 + wv * 16 + (lane & 15)) * 8];
#pragma unroll
            for (int ot = 0; ot < 4; ++ot) {
                half8 afrag = *(const half8*)&Gs[(((size_t)ks * 4 + ot) * 64 + lane) * 8];
                acc[ot] = __builtin_amdgcn_mfma_f32_16x16x32_f16(afrag, bfrag, acc[ot], 0, 0, 0);
            }
        }
    }
    // epilogue: bias + relu + store. D: m=(lane>>4)*4+r, n=lane&15.
    int h = h0 + (wv >> 1);
    int w = (wv & 1) * 16 + (lane & 15);
    float* ob = out + ((((size_t)b * 64) * 32 + d) * 32 + h) * 32 + w;
#pragma unroll
    for (int ot = 0; ot < 4; ++ot)
#pragma unroll
        for (int r = 0; r < 4; ++r) {
            int o = ot * 16 + (lane >> 4) * 4 + r;
            float v = acc[ot][r] + ws[WS_BIAS + o];
            ob[(size_t)o * 32768] = fmaxf(v, 0.f);
        }
}

extern "C" void kernel_launch(void* const* d_in, const int* in_sizes, int n_in,
                              void* d_out, int out_size, void* d_ws, size_t ws_size,
                              hipStream_t stream) {
    const float* x      = (const float*)d_in[0];
    const float* lw1    = (const float*)d_in[1];
    const float* lw2    = (const float*)d_in[2];
    const float* hw1    = (const float*)d_in[3];
    const float* hw2    = (const float*)d_in[4];
    const float* fuse_w = (const float*)d_in[5];
    const float* fuse_b = (const float*)d_in[6];
    const float* gamma  = (const float*)d_in[7];
    const float* beta   = (const float*)d_in[8];
    const float* mean   = (const float*)d_in[9];
    const float* var    = (const float*)d_in[10];
    float* ws  = (float*)d_ws;
    float* out = (float*)d_out;

    k_parity<<<2 * 64 * 8, 256, 0, stream>>>(x, ws + WS_S);
    k_att<<<2, 512, 0, stream>>>(ws + WS_S, lw1, lw2, hw1, hw2,
                                 fuse_b, gamma, beta, mean, var, ws);
    k_weights<<<2 * 64, 64, 0, stream>>>(fuse_w, ws);
    k_conv<<<2 * 32 * 16, 256, 0, stream>>>(x, ws, out);
}